// Round 6
// baseline (697.577 us; speedup 1.0000x reference)
//
#include <hip/hip_runtime.h>
#include <math.h>

#define N_TOK   16384
#define EDIM    64
#define NE      4096
#define NSLICE  8
#define CSL     (NE / NSLICE)            /* 512 codes per slice  */
#define CHUNK   128                      /* codes per LDS chunk  */
#define SEPITCH 65                       /* LDS row pitch, bank-spread */
#define ZQ_OFF  1
#define IDX_OFF (1 + N_TOK * EDIM)       /* 1048577 */
#define PERP_OFF (IDX_OFF + N_TOK)       /* 1064961 */

typedef unsigned long long u64;
typedef float v2f __attribute__((ext_vector_type(2)));
typedef float v4f __attribute__((ext_vector_type(4)));

// ---------------------------------------------------------------------------
// Kernel P (prep): per-block 64x64 LDS-tiled transpose of z into zT[j][t]
// (zT aliases the z_q output region as scratch — rewritten later by reduce),
// plus nz (tokens) and ne (codebook rows) with the exact numpy pairwise_sum
// replication (8 accs stride 8, contract off), plus hist/lossAcc zeroing.
// ---------------------------------------------------------------------------
__global__ __launch_bounds__(256) void prep_kernel(
    const float* __restrict__ z, const float* __restrict__ cb,
    float* __restrict__ zT, float* __restrict__ nz, float* __restrict__ ne,
    int* __restrict__ hist, float* __restrict__ lossAcc) {
    __shared__ float tile[64 * 65];
    const int b = blockIdx.x, t = threadIdx.x;
    {   // coalesced read of the block's 64 tokens (4096 floats contiguous)
        const v4f* src = (const v4f*)(z + (size_t)b * 64 * EDIM);
#pragma unroll
        for (int i = 0; i < 4; ++i) {
            v4f v = src[t * 4 + i];
            int f = 16 * t + 4 * i;          // flat float index in tile
            int row = f >> 6, col = f & 63;
            tile[row * 65 + col + 0] = v.x;
            tile[row * 65 + col + 1] = v.y;
            tile[row * 65 + col + 2] = v.z;
            tile[row * 65 + col + 3] = v.w;
        }
    }
    __syncthreads();
    {   // coalesced zT write: wave w -> dims 16w..16w+15, lane L -> token 64b+L
        const int w = t >> 6, L = t & 63;
#pragma unroll
        for (int jj = 0; jj < 16; ++jj) {
            int j = 16 * w + jj;
            zT[(size_t)j * N_TOK + 64 * b + L] = tile[L * 65 + j];
        }
    }
    if (t < 64) {       // nz for this block's 64 tokens (numpy pairwise)
#pragma clang fp contract(off)
        const float* row = tile + t * 65;
        float r[8];
#pragma unroll
        for (int j = 0; j < 8; ++j) { float v = row[j]; r[j] = v * v; }
#pragma unroll
        for (int bb = 8; bb < 64; bb += 8) {
#pragma unroll
            for (int j = 0; j < 8; ++j) { float v = row[bb + j]; r[j] = r[j] + v * v; }
        }
        nz[64 * b + t] = ((r[0] + r[1]) + (r[2] + r[3])) + ((r[4] + r[5]) + (r[6] + r[7]));
    } else if (t < 80) { // ne for 16 codebook rows (numpy pairwise)
#pragma clang fp contract(off)
        const float* row = cb + (size_t)(16 * b + (t - 64)) * EDIM;
        float r[8];
#pragma unroll
        for (int j = 0; j < 8; ++j) { float v = row[j]; r[j] = v * v; }
#pragma unroll
        for (int bb = 8; bb < 64; bb += 8) {
#pragma unroll
            for (int j = 0; j < 8; ++j) { float v = row[bb + j]; r[j] = r[j] + v * v; }
        }
        ne[16 * b + (t - 64)] = ((r[0] + r[1]) + (r[2] + r[3])) + ((r[4] + r[5]) + (r[6] + r[7]));
    } else if (t < 96) {
        hist[16 * b + (t - 80)] = 0;
    } else if (t == 96 && b == 0) {
        lossAcc[0] = 0.0f;
    }
}

// ---------------------------------------------------------------------------
// Kernel B (dist): lane-specialized codes + wave-uniform tokens.
// One wave = 16 tokens; lane L handles codes (kb+L, kb+64+L) of each 128-code
// chunk staged row-major (pitch 65) in LDS — e-reads are per-lane-distinct
// (banks (L+j)%32, 2-way = free), so LDS bus traffic drops 64x vs broadcast.
// z comes from transposed zT via wave-uniform loads (SGPRs); inner op is
// v_pk_fma_f32: src0 = z token-pair (SGPR pair, 1 scalar operand), src1 =
// e dim-pair with op_sel lo/hi broadcast. Each (token,code) dot is the SAME
// sequential j-ascending IEEE-FMA chain as rounds 1-5 -> d bitwise identical
// -> np.argmin ties exact. d = fma(-2,dot,tnz+ne); argmin packed
// (d_bits<<32)|k, u64 min == global first-index tie-break (d>0).
// ---------------------------------------------------------------------------
__global__ __launch_bounds__(256) void dist_argmin_kernel(
    const float* __restrict__ cb, const float* __restrict__ zT,
    const float* __restrict__ nz, const float* __restrict__ ne,
    u64* __restrict__ part) {
    __shared__ float se[CHUNK * SEPITCH];   // 33280 B
    const int tid  = threadIdx.x;
    const int wid  = __builtin_amdgcn_readfirstlane(tid >> 6);
    const int lane = tid & 63;
    const int slice = blockIdx.y;
    const int tok0  = blockIdx.x * 64 + wid * 16;

    float tnz[16];                          // wave-uniform -> SGPRs
#pragma unroll
    for (int i = 0; i < 16; ++i) tnz[i] = nz[tok0 + i];

    u64 best[16];
#pragma unroll
    for (int i = 0; i < 16; ++i) best[i] = ~0ull;

#pragma unroll 1
    for (int cc = 0; cc < CSL / CHUNK; ++cc) {
        const int kb = slice * CSL + cc * CHUNK;
        {   // stage 128 codes row-major, pitch 65 (write banks (c+j)%32, free)
            const int c = tid >> 1, h = tid & 1;
            const v4f* src = (const v4f*)(cb + (size_t)(kb + c) * EDIM + 32 * h);
            float* dst = se + SEPITCH * c + 32 * h;
#pragma unroll
            for (int r = 0; r < 8; ++r) {
                v4f v = src[r];
                dst[4 * r + 0] = v.x; dst[4 * r + 1] = v.y;
                dst[4 * r + 2] = v.z; dst[4 * r + 3] = v.w;
            }
        }
        __syncthreads();

        const int k0 = kb + lane, k1 = kb + 64 + lane;
        const float ne0 = ne[k0], ne1 = ne[k1];
        v2f acc[8][2];
#pragma unroll
        for (int p = 0; p < 8; ++p) {
            acc[p][0] = (v2f){0.f, 0.f};
            acc[p][1] = (v2f){0.f, 0.f};
        }
        const float* e0p = se + SEPITCH * lane;
        const float* e1p = se + SEPITCH * (lane + 64);
#pragma unroll
        for (int jp = 0; jp < 32; ++jp) {
            const int j = 2 * jp;
            v2f e0 = { e0p[j], e0p[j + 1] };
            v2f e1 = { e1p[j], e1p[j + 1] };
            const float* zj0 = zT + (size_t)j * N_TOK + tok0;
            const float* zj1 = zj0 + N_TOK;
#pragma unroll
            for (int p = 0; p < 8; ++p) {
                union { float f[2]; u64 u; } za, zb;
                za.f[0] = zj0[2 * p]; za.f[1] = zj0[2 * p + 1];
                zb.f[0] = zj1[2 * p]; zb.f[1] = zj1[2 * p + 1];
                asm("v_pk_fma_f32 %0, %1, %2, %0 op_sel:[0,0,0] op_sel_hi:[1,0,1]"
                    : "+v"(acc[p][0]) : "s"(za.u), "v"(e0));
                asm("v_pk_fma_f32 %0, %1, %2, %0 op_sel:[0,1,0] op_sel_hi:[1,1,1]"
                    : "+v"(acc[p][0]) : "s"(zb.u), "v"(e0));
                asm("v_pk_fma_f32 %0, %1, %2, %0 op_sel:[0,0,0] op_sel_hi:[1,0,1]"
                    : "+v"(acc[p][1]) : "s"(za.u), "v"(e1));
                asm("v_pk_fma_f32 %0, %1, %2, %0 op_sel:[0,1,0] op_sel_hi:[1,1,1]"
                    : "+v"(acc[p][1]) : "s"(zb.u), "v"(e1));
            }
        }
#pragma unroll
        for (int p = 0; p < 8; ++p) {
            float s0 = tnz[2 * p]     + ne0;
            float s1 = tnz[2 * p + 1] + ne0;
            float s2 = tnz[2 * p]     + ne1;
            float s3 = tnz[2 * p + 1] + ne1;
            float t00 = __builtin_fmaf(-2.f, acc[p][0].x, s0);
            float t10 = __builtin_fmaf(-2.f, acc[p][0].y, s1);
            float t01 = __builtin_fmaf(-2.f, acc[p][1].x, s2);
            float t11 = __builtin_fmaf(-2.f, acc[p][1].y, s3);
            u64 q;
            q = ((u64)__float_as_uint(t00) << 32) | (u64)k0; if (q < best[2 * p])     best[2 * p]     = q;
            q = ((u64)__float_as_uint(t01) << 32) | (u64)k1; if (q < best[2 * p])     best[2 * p]     = q;
            q = ((u64)__float_as_uint(t10) << 32) | (u64)k0; if (q < best[2 * p + 1]) best[2 * p + 1] = q;
            q = ((u64)__float_as_uint(t11) << 32) | (u64)k1; if (q < best[2 * p + 1]) best[2 * p + 1] = q;
        }
        __syncthreads();
    }

    // cross-lane u64-min butterfly (keeps global first-index tie-break)
#pragma unroll
    for (int i = 0; i < 16; ++i) {
        u64 b = best[i];
#pragma unroll
        for (int off = 32; off > 0; off >>= 1) {
            u64 o = __shfl_xor((unsigned long long)b, off, 64);
            if (o < b) b = o;
        }
        if (lane == 0) part[(size_t)slice * N_TOK + tok0 + i] = b;
    }
}

// ---------------------------------------------------------------------------
// Kernel C: combine slice partials, idx/hist, gather z_q, write
// z_q_st = z + (z_q - z), accumulate sum((z_q - z)^2). 4 threads per token.
// ---------------------------------------------------------------------------
__global__ __launch_bounds__(256) void reduce_gather_kernel(
    const float* __restrict__ z, const float* __restrict__ cb,
    const u64* __restrict__ part, int* __restrict__ hist,
    float* __restrict__ lossAcc, float* __restrict__ out) {
    const int id = blockIdx.x * 256 + threadIdx.x;
    const int tok = id >> 2, q = id & 3;
    u64 best = part[tok];
#pragma unroll
    for (int s = 1; s < NSLICE; ++s) {
        u64 p = part[(size_t)s * N_TOK + tok];
        if (p < best) best = p;
    }
    const int idx = (int)(best & 0xFFFFFFFFull);
    if (q == 0) { out[IDX_OFF + tok] = (float)idx; atomicAdd(&hist[idx], 1); }

    const float* ev = cb + (size_t)idx * EDIM + 16 * q;
    const float* zv = z + (size_t)tok * EDIM + 16 * q;
    float* o = out + ZQ_OFF + (size_t)tok * EDIM + 16 * q;
    float acc = 0.f;
#pragma unroll
    for (int i = 0; i < 16; ++i) {
        float e = ev[i], zz = zv[i];
        float d = e - zz;
        o[i] = zz + d;
        acc = __builtin_fmaf(d, d, acc);
    }
    __shared__ float red[256];
    red[threadIdx.x] = acc;
    __syncthreads();
    for (int s = 128; s > 0; s >>= 1) {
        if (threadIdx.x < s) red[threadIdx.x] += red[threadIdx.x + s];
        __syncthreads();
    }
    if (threadIdx.x == 0) atomicAdd(lossAcc, red[0]);
}

// ---------------------------------------------------------------------------
// Kernel D: perplexity + loss finalize.
// ---------------------------------------------------------------------------
__global__ __launch_bounds__(256) void finalize_kernel(
    const int* __restrict__ hist, const float* __restrict__ lossAcc,
    float* __restrict__ out) {
    __shared__ float red[256];
    float acc = 0.0f;
    for (int i = threadIdx.x; i < NE; i += 256) {
        float e = (float)hist[i] * (1.0f / 16384.0f);
        acc += e * logf(e + 1e-10f);
    }
    red[threadIdx.x] = acc;
    __syncthreads();
    for (int s = 128; s > 0; s >>= 1) {
        if (threadIdx.x < s) red[threadIdx.x] += red[threadIdx.x + s];
        __syncthreads();
    }
    if (threadIdx.x == 0) {
        out[PERP_OFF] = expf(-red[0]);
        float m = lossAcc[0] * (1.0f / 1048576.0f);
        out[0] = m + 0.25f * m;
    }
}

extern "C" void kernel_launch(void* const* d_in, const int* in_sizes, int n_in,
                              void* d_out, int out_size, void* d_ws, size_t ws_size,
                              hipStream_t stream) {
    const float* z  = (const float*)d_in[0];
    const float* cb = (const float*)d_in[1];
    float* out = (float*)d_out;

    char* ws = (char*)d_ws;
    u64*   part    = (u64*)ws;                                   // 1 MB
    float* nz      = (float*)(ws + (size_t)NSLICE * N_TOK * 8);  // 64 KB
    float* ne      = nz + N_TOK;                                 // 16 KB
    int*   hist    = (int*)(ne + NE);                            // 16 KB
    float* lossAcc = (float*)(hist + NE);                        // 4 B
    float* zT      = out + ZQ_OFF;   // z_q region doubles as zT scratch;
                                     // rewritten by reduce_gather afterwards

    hipLaunchKernelGGL(prep_kernel, dim3(256), dim3(256), 0, stream,
                       z, cb, zT, nz, ne, hist, lossAcc);
    hipLaunchKernelGGL(dist_argmin_kernel, dim3(256, NSLICE), dim3(256), 0, stream,
                       cb, zT, nz, ne, part);
    hipLaunchKernelGGL(reduce_gather_kernel, dim3(256), dim3(256), 0, stream,
                       z, cb, part, hist, lossAcc, out);
    hipLaunchKernelGGL(finalize_kernel, dim3(1), dim3(256), 0, stream,
                       hist, lossAcc, out);
}

// Round 7
// 359.366 us; speedup vs baseline: 1.9411x; 1.9411x over previous
//
#include <hip/hip_runtime.h>
#include <math.h>

#define N_TOK   16384
#define EDIM    64
#define NE      4096
#define CHUNK   128                      /* codes staged per LDS chunk */
#define TPB     256
#define TOKPT   4                        /* tokens per thread          */
#define ZQ_OFF  1
#define IDX_OFF (1 + N_TOK * EDIM)       /* 1048577 */
#define PERP_OFF (IDX_OFF + N_TOK)       /* 1064961 */

typedef unsigned long long u64;
typedef float v2f __attribute__((ext_vector_type(2)));
typedef float v4f __attribute__((ext_vector_type(4)));

// ---------------------------------------------------------------------------
// Kernel B (fused norms + zeroing): distances + per-slice argmin.
// One thread = FOUR tokens, two interleaved v2f arrays (zpA = tokens 0,1;
// zpB = tokens 2,3) resident in 128 VGPRs (interleaved layout forces
// residency — r5 evidence). Codebook chunk (128 codes, 32 KB) staged in LDS,
// read as wave-uniform broadcast float4s. Each broadcast b128 (4 dims of one
// code) now feeds 16 FMAs = 8 pk_fma -> VALU-bound (32 cyc VALU vs 24 cyc
// LDS per q-step), fixing r5's LDS-bus wall. Inner op is v_pk_fma_f32 with
// op_sel broadcast of the code element (r5-proven bit-exact):
//   lo-broadcast: op_sel:[0,0,0] op_sel_hi:[1,0,1]  (src1.lo both halves)
//   hi-broadcast: op_sel:[0,1,0] op_sel_hi:[1,1,1]  (src1.hi both halves)
// Each (token,code) dot is the SAME sequential j-ascending IEEE-FMA chain as
// all passing rounds -> d bitwise identical -> np.argmin ties exact.
// d = fma(-2, dot, tnz + ne[k]); argmin packed (d_bits<<32)|k, u64 min ==
// first-index tie-break (d > 0 so float bits monotone).
// NSLICE=32 -> grid (16,32) = 512 blocks = exactly 2 blocks/CU resident
// under __launch_bounds__(256,2); one 128-code chunk per block.
// ---------------------------------------------------------------------------
__global__ __launch_bounds__(256, 2) void dist_argmin_kernel(
    const float* __restrict__ z, const float* __restrict__ cb,
    u64* __restrict__ part, int* __restrict__ hist,
    float* __restrict__ lossAcc, int nslice) {
    __shared__ float se[CHUNK * EDIM];   // 32 KB
    __shared__ float sne[CHUNK];
    const int tid    = threadIdx.x;
    const int token0 = blockIdx.x * (TPB * TOKPT) + tid;  // +0,+256,+512,+768
    const int slice  = blockIdx.y;
    const int kb     = slice * (NE / nslice);             // one chunk per block

    if (slice == 0) {                    // grid.x*TPB = 4096 = NE
        int gid = blockIdx.x * TPB + tid;
        if (gid < NE) hist[gid] = 0;
        if (gid == 0) lossAcc[0] = 0.0f;
    }

    // Load 4 tokens, interleave pairs: zpA[j]=(z0[j],z1[j]), zpB[j]=(z2[j],z3[j])
    v2f zpA[EDIM], zpB[EDIM];
    {
        const v4f* p0 = (const v4f*)(z + (size_t)(token0 + 0 * TPB) * EDIM);
        const v4f* p1 = (const v4f*)(z + (size_t)(token0 + 1 * TPB) * EDIM);
        const v4f* p2 = (const v4f*)(z + (size_t)(token0 + 2 * TPB) * EDIM);
        const v4f* p3 = (const v4f*)(z + (size_t)(token0 + 3 * TPB) * EDIM);
#pragma unroll
        for (int q = 0; q < 16; ++q) {
            v4f a = p0[q], b = p1[q], c = p2[q], d = p3[q];
            zpA[4 * q + 0].x = a.x; zpA[4 * q + 0].y = b.x;
            zpA[4 * q + 1].x = a.y; zpA[4 * q + 1].y = b.y;
            zpA[4 * q + 2].x = a.z; zpA[4 * q + 2].y = b.z;
            zpA[4 * q + 3].x = a.w; zpA[4 * q + 3].y = b.w;
            zpB[4 * q + 0].x = c.x; zpB[4 * q + 0].y = d.x;
            zpB[4 * q + 1].x = c.y; zpB[4 * q + 1].y = d.y;
            zpB[4 * q + 2].x = c.z; zpB[4 * q + 2].y = d.z;
            zpB[4 * q + 3].x = c.w; zpB[4 * q + 3].y = d.w;
        }
    }
    // nz for the 4 tokens: exact numpy pairwise_sum replication (contract off)
    float tnz0, tnz1, tnz2, tnz3;
    {
#pragma clang fp contract(off)
        float r0[8], r1[8], r2[8], r3[8];
#pragma unroll
        for (int j = 0; j < 8; ++j) {
            float a = zpA[j].x, b = zpA[j].y, c = zpB[j].x, d = zpB[j].y;
            r0[j] = a * a; r1[j] = b * b; r2[j] = c * c; r3[j] = d * d;
        }
#pragma unroll
        for (int bb = 8; bb < 64; bb += 8) {
#pragma unroll
            for (int j = 0; j < 8; ++j) {
                float a = zpA[bb + j].x, b = zpA[bb + j].y;
                float c = zpB[bb + j].x, d = zpB[bb + j].y;
                r0[j] = r0[j] + a * a; r1[j] = r1[j] + b * b;
                r2[j] = r2[j] + c * c; r3[j] = r3[j] + d * d;
            }
        }
        tnz0 = ((r0[0] + r0[1]) + (r0[2] + r0[3])) + ((r0[4] + r0[5]) + (r0[6] + r0[7]));
        tnz1 = ((r1[0] + r1[1]) + (r1[2] + r1[3])) + ((r1[4] + r1[5]) + (r1[6] + r1[7]));
        tnz2 = ((r2[0] + r2[1]) + (r2[2] + r2[3])) + ((r2[4] + r2[5]) + (r2[6] + r2[7]));
        tnz3 = ((r3[0] + r3[1]) + (r3[2] + r3[3])) + ((r3[4] + r3[5]) + (r3[6] + r3[7]));
    }

    {   // stage 128 codes -> LDS (coalesced b128, conflict-free)
        const v4f* src = (const v4f*)(cb + (size_t)kb * EDIM);
        v4f* dst = (v4f*)se;
#pragma unroll
        for (int r = 0; r < (CHUNK * EDIM / 4) / TPB; ++r)
            dst[r * TPB + tid] = src[r * TPB + tid];
    }
    if (tid < CHUNK) {
#pragma clang fp contract(off)
        // ne for staged codes, numpy pairwise replication
        const v4f* cr = (const v4f*)(cb + (size_t)(kb + tid) * EDIM);
        float r[8];
        {
            v4f c0 = cr[0], c1 = cr[1];
            r[0] = c0.x * c0.x; r[1] = c0.y * c0.y;
            r[2] = c0.z * c0.z; r[3] = c0.w * c0.w;
            r[4] = c1.x * c1.x; r[5] = c1.y * c1.y;
            r[6] = c1.z * c1.z; r[7] = c1.w * c1.w;
        }
#pragma unroll
        for (int b = 1; b < 8; ++b) {
            v4f a = cr[2 * b], d = cr[2 * b + 1];
            r[0] = r[0] + a.x * a.x; r[1] = r[1] + a.y * a.y;
            r[2] = r[2] + a.z * a.z; r[3] = r[3] + a.w * a.w;
            r[4] = r[4] + d.x * d.x; r[5] = r[5] + d.y * d.y;
            r[6] = r[6] + d.z * d.z; r[7] = r[7] + d.w * d.w;
        }
        sne[tid] = ((r[0] + r[1]) + (r[2] + r[3])) + ((r[4] + r[5]) + (r[6] + r[7]));
    }
    __syncthreads();

    u64 best0 = ~0ull, best1 = ~0ull, best2 = ~0ull, best3 = ~0ull;
#pragma unroll 1
    for (int k = 0; k < CHUNK; k += 2) {
        const v4f* e0 = (const v4f*)(se + (size_t)(k + 0) * EDIM);
        const v4f* e1 = (const v4f*)(se + (size_t)(k + 1) * EDIM);
        v2f aA0 = {0.f, 0.f}, aA1 = {0.f, 0.f};   // tokens 0,1 x codes k,k+1
        v2f aB0 = {0.f, 0.f}, aB1 = {0.f, 0.f};   // tokens 2,3 x codes k,k+1
#pragma unroll
        for (int q = 0; q < 16; ++q) {
            v4f A = e0[q], B = e1[q];
            v2f Alo = __builtin_shufflevector(A, A, 0, 1);
            v2f Ahi = __builtin_shufflevector(A, A, 2, 3);
            v2f Blo = __builtin_shufflevector(B, B, 0, 1);
            v2f Bhi = __builtin_shufflevector(B, B, 2, 3);
            asm("v_pk_fma_f32 %0, %1, %2, %0 op_sel:[0,0,0] op_sel_hi:[1,0,1]"
                : "+v"(aA0) : "v"(zpA[4 * q + 0]), "v"(Alo));
            asm("v_pk_fma_f32 %0, %1, %2, %0 op_sel:[0,1,0] op_sel_hi:[1,1,1]"
                : "+v"(aA0) : "v"(zpA[4 * q + 1]), "v"(Alo));
            asm("v_pk_fma_f32 %0, %1, %2, %0 op_sel:[0,0,0] op_sel_hi:[1,0,1]"
                : "+v"(aA0) : "v"(zpA[4 * q + 2]), "v"(Ahi));
            asm("v_pk_fma_f32 %0, %1, %2, %0 op_sel:[0,1,0] op_sel_hi:[1,1,1]"
                : "+v"(aA0) : "v"(zpA[4 * q + 3]), "v"(Ahi));
            asm("v_pk_fma_f32 %0, %1, %2, %0 op_sel:[0,0,0] op_sel_hi:[1,0,1]"
                : "+v"(aA1) : "v"(zpA[4 * q + 0]), "v"(Blo));
            asm("v_pk_fma_f32 %0, %1, %2, %0 op_sel:[0,1,0] op_sel_hi:[1,1,1]"
                : "+v"(aA1) : "v"(zpA[4 * q + 1]), "v"(Blo));
            asm("v_pk_fma_f32 %0, %1, %2, %0 op_sel:[0,0,0] op_sel_hi:[1,0,1]"
                : "+v"(aA1) : "v"(zpA[4 * q + 2]), "v"(Bhi));
            asm("v_pk_fma_f32 %0, %1, %2, %0 op_sel:[0,1,0] op_sel_hi:[1,1,1]"
                : "+v"(aA1) : "v"(zpA[4 * q + 3]), "v"(Bhi));
            asm("v_pk_fma_f32 %0, %1, %2, %0 op_sel:[0,0,0] op_sel_hi:[1,0,1]"
                : "+v"(aB0) : "v"(zpB[4 * q + 0]), "v"(Alo));
            asm("v_pk_fma_f32 %0, %1, %2, %0 op_sel:[0,1,0] op_sel_hi:[1,1,1]"
                : "+v"(aB0) : "v"(zpB[4 * q + 1]), "v"(Alo));
            asm("v_pk_fma_f32 %0, %1, %2, %0 op_sel:[0,0,0] op_sel_hi:[1,0,1]"
                : "+v"(aB0) : "v"(zpB[4 * q + 2]), "v"(Ahi));
            asm("v_pk_fma_f32 %0, %1, %2, %0 op_sel:[0,1,0] op_sel_hi:[1,1,1]"
                : "+v"(aB0) : "v"(zpB[4 * q + 3]), "v"(Ahi));
            asm("v_pk_fma_f32 %0, %1, %2, %0 op_sel:[0,0,0] op_sel_hi:[1,0,1]"
                : "+v"(aB1) : "v"(zpB[4 * q + 0]), "v"(Blo));
            asm("v_pk_fma_f32 %0, %1, %2, %0 op_sel:[0,1,0] op_sel_hi:[1,1,1]"
                : "+v"(aB1) : "v"(zpB[4 * q + 1]), "v"(Blo));
            asm("v_pk_fma_f32 %0, %1, %2, %0 op_sel:[0,0,0] op_sel_hi:[1,0,1]"
                : "+v"(aB1) : "v"(zpB[4 * q + 2]), "v"(Bhi));
            asm("v_pk_fma_f32 %0, %1, %2, %0 op_sel:[0,1,0] op_sel_hi:[1,1,1]"
                : "+v"(aB1) : "v"(zpB[4 * q + 3]), "v"(Bhi));
        }
        const float s0 = sne[k + 0], s1 = sne[k + 1];
        float t00 = __builtin_fmaf(-2.f, aA0.x, tnz0 + s0);
        float t10 = __builtin_fmaf(-2.f, aA0.y, tnz1 + s0);
        float t20 = __builtin_fmaf(-2.f, aB0.x, tnz2 + s0);
        float t30 = __builtin_fmaf(-2.f, aB0.y, tnz3 + s0);
        float t01 = __builtin_fmaf(-2.f, aA1.x, tnz0 + s1);
        float t11 = __builtin_fmaf(-2.f, aA1.y, tnz1 + s1);
        float t21 = __builtin_fmaf(-2.f, aB1.x, tnz2 + s1);
        float t31 = __builtin_fmaf(-2.f, aB1.y, tnz3 + s1);
        u64 p;
        p = ((u64)__float_as_uint(t00) << 32) | (u64)(kb + k + 0); if (p < best0) best0 = p;
        p = ((u64)__float_as_uint(t01) << 32) | (u64)(kb + k + 1); if (p < best0) best0 = p;
        p = ((u64)__float_as_uint(t10) << 32) | (u64)(kb + k + 0); if (p < best1) best1 = p;
        p = ((u64)__float_as_uint(t11) << 32) | (u64)(kb + k + 1); if (p < best1) best1 = p;
        p = ((u64)__float_as_uint(t20) << 32) | (u64)(kb + k + 0); if (p < best2) best2 = p;
        p = ((u64)__float_as_uint(t21) << 32) | (u64)(kb + k + 1); if (p < best2) best2 = p;
        p = ((u64)__float_as_uint(t30) << 32) | (u64)(kb + k + 0); if (p < best3) best3 = p;
        p = ((u64)__float_as_uint(t31) << 32) | (u64)(kb + k + 1); if (p < best3) best3 = p;
    }
    part[(size_t)slice * N_TOK + token0 + 0 * TPB] = best0;
    part[(size_t)slice * N_TOK + token0 + 1 * TPB] = best1;
    part[(size_t)slice * N_TOK + token0 + 2 * TPB] = best2;
    part[(size_t)slice * N_TOK + token0 + 3 * TPB] = best3;
}

// ---------------------------------------------------------------------------
// Kernel C: combine nslice slice-partials (u64 min keeps first-index
// tie-break), write idx as float, histogram, gather z_q, write
// z_q_st = z + (z_q - z), accumulate sum((z_q - z)^2). 4 threads per token.
// ---------------------------------------------------------------------------
__global__ __launch_bounds__(256) void reduce_gather_kernel(
    const float* __restrict__ z, const float* __restrict__ cb,
    const u64* __restrict__ part, int* __restrict__ hist,
    float* __restrict__ lossAcc, float* __restrict__ out, int nslice) {
    const int id = blockIdx.x * 256 + threadIdx.x;
    const int tok = id >> 2, q = id & 3;
    u64 best = part[tok];
    for (int s = 1; s < nslice; ++s) {
        u64 p = part[(size_t)s * N_TOK + tok];
        if (p < best) best = p;
    }
    const int idx = (int)(best & 0xFFFFFFFFull);
    if (q == 0) { out[IDX_OFF + tok] = (float)idx; atomicAdd(&hist[idx], 1); }

    const float* ev = cb + (size_t)idx * EDIM + 16 * q;
    const float* zv = z + (size_t)tok * EDIM + 16 * q;
    float* o = out + ZQ_OFF + (size_t)tok * EDIM + 16 * q;
    float acc = 0.f;
#pragma unroll
    for (int i = 0; i < 16; ++i) {
        float e = ev[i], zz = zv[i];
        float d = e - zz;
        o[i] = zz + d;
        acc = __builtin_fmaf(d, d, acc);
    }
    __shared__ float red[256];
    red[threadIdx.x] = acc;
    __syncthreads();
    for (int s = 128; s > 0; s >>= 1) {
        if (threadIdx.x < s) red[threadIdx.x] += red[threadIdx.x + s];
        __syncthreads();
    }
    if (threadIdx.x == 0) atomicAdd(lossAcc, red[0]);
}

// ---------------------------------------------------------------------------
// Kernel D: perplexity from histogram + loss finalize.
// ---------------------------------------------------------------------------
__global__ __launch_bounds__(256) void finalize_kernel(
    const int* __restrict__ hist, const float* __restrict__ lossAcc,
    float* __restrict__ out) {
    __shared__ float red[256];
    float acc = 0.0f;
    for (int i = threadIdx.x; i < NE; i += 256) {
        float e = (float)hist[i] * (1.0f / 16384.0f);  // exact /n_tokens
        acc += e * logf(e + 1e-10f);
    }
    red[threadIdx.x] = acc;
    __syncthreads();
    for (int s = 128; s > 0; s >>= 1) {
        if (threadIdx.x < s) red[threadIdx.x] += red[threadIdx.x + s];
        __syncthreads();
    }
    if (threadIdx.x == 0) {
        out[PERP_OFF] = expf(-red[0]);
        float m = lossAcc[0] * (1.0f / 1048576.0f);    // exact /B*T*E
        out[0] = m + 0.25f * m;
    }
}

extern "C" void kernel_launch(void* const* d_in, const int* in_sizes, int n_in,
                              void* d_out, int out_size, void* d_ws, size_t ws_size,
                              hipStream_t stream) {
    const float* z  = (const float*)d_in[0];
    const float* cb = (const float*)d_in[1];
    float* out = (float*)d_out;

    // 32 slices (grid (16,32) = 512 blocks = 2/CU) if ws fits the 4 MB
    // partial array, else 16 slices (2 MB, 256 blocks).
    const size_t need32 = (size_t)32 * N_TOK * 8 + (size_t)(NE + 1) * 4;
    const int nslice = (ws_size >= need32) ? 32 : 16;

    char* ws = (char*)d_ws;
    u64*   part    = (u64*)ws;                                    // nslice*16384*8
    int*   hist    = (int*)(ws + (size_t)nslice * N_TOK * 8);     // 16 KB
    float* lossAcc = (float*)(hist + NE);                         // 4 B

    hipLaunchKernelGGL(dist_argmin_kernel,
                       dim3(N_TOK / (TPB * TOKPT), nslice), dim3(TPB), 0, stream,
                       z, cb, part, hist, lossAcc, nslice);
    hipLaunchKernelGGL(reduce_gather_kernel, dim3(256), dim3(256), 0, stream,
                       z, cb, part, hist, lossAcc, out, nslice);
    hipLaunchKernelGGL(finalize_kernel, dim3(1), dim3(256), 0, stream,
                       hist, lossAcc, out);
}

// Round 8
// 264.119 us; speedup vs baseline: 2.6411x; 1.3606x over previous
//
#include <hip/hip_runtime.h>
#include <math.h>

#define N_TOK   16384
#define EDIM    64
#define NE      4096
#define TPB     256
#define TOKPT   2                        /* tokens per thread          */
#define ZQ_OFF  1
#define IDX_OFF (1 + N_TOK * EDIM)       /* 1048577 */
#define PERP_OFF (IDX_OFF + N_TOK)       /* 1064961 */

typedef unsigned long long u64;
typedef float v2f __attribute__((ext_vector_type(2)));
typedef float v4f __attribute__((ext_vector_type(4)));

// ---------------------------------------------------------------------------
// Kernel P (prep): ne[k] = ||e_k||^2 with the exact numpy pairwise_sum
// replication (8 accs stride 8, contract off), plus hist/lossAcc zeroing.
// grid 16 x 256 = 4096 threads, one codebook row each.
// ---------------------------------------------------------------------------
__global__ __launch_bounds__(256) void prep_kernel(
    const float* __restrict__ cb, float* __restrict__ ne,
    int* __restrict__ hist, float* __restrict__ lossAcc) {
#pragma clang fp contract(off)
    const int i = blockIdx.x * 256 + threadIdx.x;
    hist[i] = 0;
    if (i == 0) lossAcc[0] = 0.0f;
    const float* row = cb + (size_t)i * EDIM;
    float r[8];
#pragma unroll
    for (int j = 0; j < 8; ++j) { float v = row[j]; r[j] = v * v; }
#pragma unroll
    for (int b = 8; b < 64; b += 8) {
#pragma unroll
        for (int j = 0; j < 8; ++j) { float v = row[b + j]; r[j] = r[j] + v * v; }
    }
    ne[i] = ((r[0] + r[1]) + (r[2] + r[3])) + ((r[4] + r[5]) + (r[6] + r[7]));
}

// ---------------------------------------------------------------------------
// Kernel B (dist): scalar-pipe e-delivery, NO LDS.
// One thread = TWO tokens interleaved as zp[j] = (z0[j], z1[j]) in 128 VGPRs
// (r5-proven resident). The codebook row for code k is wave-uniform: its
// address is built from a readfirstlane'd base, so the compiler emits s_load
// (constant cache, scalar pipe) — the LDS pipe (r5's 164 µs wall: 16.8M/TOKPT
// broadcast b128 x 12 cyc) is bypassed entirely. Inner op: v_pk_fma_f32 with
// src0 = z token-pair (VGPR), src1 = e dim-pair in an SGPR pair (1 scalar
// operand, legal), op_sel broadcasting lo/hi — the r5/r7-proven encoding:
//   lo: op_sel:[0,0,0] op_sel_hi:[1,0,1]   hi: op_sel:[0,1,0] op_sel_hi:[1,1,1]
// Each (token,code) dot is the SAME sequential j-ascending IEEE-FMA chain as
// every passing round -> d bitwise identical -> np.argmin ties exact.
// 2 codes in flight = 2 independent acc chains (x2 waves/SIMD) covers FMA
// latency. d = fma(-2, dot, tnz + ne[k]); argmin packed (d_bits<<32)|k,
// u64 min == first-index tie-break (d > 0 so float bits monotone).
// ---------------------------------------------------------------------------
__global__ __launch_bounds__(256, 2) void dist_argmin_kernel(
    const float* __restrict__ z, const float* __restrict__ cb,
    const float* __restrict__ ne, u64* __restrict__ part, int csl) {
    const int tid    = threadIdx.x;
    const int token0 = blockIdx.x * (TPB * TOKPT) + tid;   // tokens tid, tid+256
    const int token1 = token0 + TPB;
    const int kb     = __builtin_amdgcn_readfirstlane(blockIdx.y * csl);

    // Load both tokens interleaved (b128 global loads, coalesced).
    v2f zp[EDIM];
    {
        const v4f* p0 = (const v4f*)(z + (size_t)token0 * EDIM);
        const v4f* p1 = (const v4f*)(z + (size_t)token1 * EDIM);
#pragma unroll
        for (int q = 0; q < 16; ++q) {
            v4f a = p0[q], b = p1[q];
            zp[4 * q + 0].x = a.x; zp[4 * q + 0].y = b.x;
            zp[4 * q + 1].x = a.y; zp[4 * q + 1].y = b.y;
            zp[4 * q + 2].x = a.z; zp[4 * q + 2].y = b.z;
            zp[4 * q + 3].x = a.w; zp[4 * q + 3].y = b.w;
        }
    }
    // nz for the 2 tokens: exact numpy pairwise_sum replication (contract off)
    float tnz0, tnz1;
    {
#pragma clang fp contract(off)
        float r0[8], r1[8];
#pragma unroll
        for (int j = 0; j < 8; ++j) {
            float a = zp[j].x, b = zp[j].y;
            r0[j] = a * a; r1[j] = b * b;
        }
#pragma unroll
        for (int bb = 8; bb < 64; bb += 8) {
#pragma unroll
            for (int j = 0; j < 8; ++j) {
                float a = zp[bb + j].x, b = zp[bb + j].y;
                r0[j] = r0[j] + a * a; r1[j] = r1[j] + b * b;
            }
        }
        tnz0 = ((r0[0] + r0[1]) + (r0[2] + r0[3])) + ((r0[4] + r0[5]) + (r0[6] + r0[7]));
        tnz1 = ((r1[0] + r1[1]) + (r1[2] + r1[3])) + ((r1[4] + r1[5]) + (r1[6] + r1[7]));
    }

    u64 best0 = ~0ull, best1 = ~0ull;
#pragma unroll 1
    for (int kk = 0; kk < csl; kk += 2) {
        const int k = kb + kk;                     // wave-uniform
        const u64* e0 = (const u64*)(cb + (size_t)(k + 0) * EDIM);
        const u64* e1 = (const u64*)(cb + (size_t)(k + 1) * EDIM);
        v2f a0 = {0.f, 0.f}, a1 = {0.f, 0.f};
#pragma unroll
        for (int jp = 0; jp < 32; ++jp) {
            u64 w0 = e0[jp];                       // uniform -> s_load
            u64 w1 = e1[jp];
            asm("v_pk_fma_f32 %0, %1, %2, %0 op_sel:[0,0,0] op_sel_hi:[1,0,1]"
                : "+v"(a0) : "v"(zp[2 * jp + 0]), "s"(w0));
            asm("v_pk_fma_f32 %0, %1, %2, %0 op_sel:[0,1,0] op_sel_hi:[1,1,1]"
                : "+v"(a0) : "v"(zp[2 * jp + 1]), "s"(w0));
            asm("v_pk_fma_f32 %0, %1, %2, %0 op_sel:[0,0,0] op_sel_hi:[1,0,1]"
                : "+v"(a1) : "v"(zp[2 * jp + 0]), "s"(w1));
            asm("v_pk_fma_f32 %0, %1, %2, %0 op_sel:[0,1,0] op_sel_hi:[1,1,1]"
                : "+v"(a1) : "v"(zp[2 * jp + 1]), "s"(w1));
        }
        const float s0 = ne[k], s1 = ne[k + 1];    // uniform -> s_load
        float t00 = __builtin_fmaf(-2.f, a0.x, tnz0 + s0);
        float t10 = __builtin_fmaf(-2.f, a0.y, tnz1 + s0);
        float t01 = __builtin_fmaf(-2.f, a1.x, tnz0 + s1);
        float t11 = __builtin_fmaf(-2.f, a1.y, tnz1 + s1);
        u64 p;
        p = ((u64)__float_as_uint(t00) << 32) | (u64)(k + 0); if (p < best0) best0 = p;
        p = ((u64)__float_as_uint(t01) << 32) | (u64)(k + 1); if (p < best0) best0 = p;
        p = ((u64)__float_as_uint(t10) << 32) | (u64)(k + 0); if (p < best1) best1 = p;
        p = ((u64)__float_as_uint(t11) << 32) | (u64)(k + 1); if (p < best1) best1 = p;
    }
    part[(size_t)blockIdx.y * N_TOK + token0] = best0;
    part[(size_t)blockIdx.y * N_TOK + token1] = best1;
}

// ---------------------------------------------------------------------------
// Kernel C: combine nslice slice-partials (u64 min keeps first-index
// tie-break), write idx as float, histogram, gather z_q, write
// z_q_st = z + (z_q - z), accumulate sum((z_q - z)^2). 4 threads per token.
// ---------------------------------------------------------------------------
__global__ __launch_bounds__(256) void reduce_gather_kernel(
    const float* __restrict__ z, const float* __restrict__ cb,
    const u64* __restrict__ part, int* __restrict__ hist,
    float* __restrict__ lossAcc, float* __restrict__ out, int nslice) {
    const int id = blockIdx.x * 256 + threadIdx.x;
    const int tok = id >> 2, q = id & 3;
    u64 best = part[tok];
    for (int s = 1; s < nslice; ++s) {
        u64 p = part[(size_t)s * N_TOK + tok];
        if (p < best) best = p;
    }
    const int idx = (int)(best & 0xFFFFFFFFull);
    if (q == 0) { out[IDX_OFF + tok] = (float)idx; atomicAdd(&hist[idx], 1); }

    const float* ev = cb + (size_t)idx * EDIM + 16 * q;
    const float* zv = z + (size_t)tok * EDIM + 16 * q;
    float* o = out + ZQ_OFF + (size_t)tok * EDIM + 16 * q;
    float acc = 0.f;
#pragma unroll
    for (int i = 0; i < 16; ++i) {
        float e = ev[i], zz = zv[i];
        float d = e - zz;
        o[i] = zz + d;
        acc = __builtin_fmaf(d, d, acc);
    }
    __shared__ float red[256];
    red[threadIdx.x] = acc;
    __syncthreads();
    for (int s = 128; s > 0; s >>= 1) {
        if (threadIdx.x < s) red[threadIdx.x] += red[threadIdx.x + s];
        __syncthreads();
    }
    if (threadIdx.x == 0) atomicAdd(lossAcc, red[0]);
}

// ---------------------------------------------------------------------------
// Kernel D: perplexity from histogram + loss finalize.
// ---------------------------------------------------------------------------
__global__ __launch_bounds__(256) void finalize_kernel(
    const int* __restrict__ hist, const float* __restrict__ lossAcc,
    float* __restrict__ out) {
    __shared__ float red[256];
    float acc = 0.0f;
    for (int i = threadIdx.x; i < NE; i += 256) {
        float e = (float)hist[i] * (1.0f / 16384.0f);  // exact /n_tokens
        acc += e * logf(e + 1e-10f);
    }
    red[threadIdx.x] = acc;
    __syncthreads();
    for (int s = 128; s > 0; s >>= 1) {
        if (threadIdx.x < s) red[threadIdx.x] += red[threadIdx.x + s];
        __syncthreads();
    }
    if (threadIdx.x == 0) {
        out[PERP_OFF] = expf(-red[0]);
        float m = lossAcc[0] * (1.0f / 1048576.0f);    // exact /B*T*E
        out[0] = m + 0.25f * m;
    }
}

extern "C" void kernel_launch(void* const* d_in, const int* in_sizes, int n_in,
                              void* d_out, int out_size, void* d_ws, size_t ws_size,
                              hipStream_t stream) {
    const float* z  = (const float*)d_in[0];
    const float* cb = (const float*)d_in[1];
    float* out = (float*)d_out;

    // 16 slices (grid (32,16) = 512 blocks = 2/CU) if ws fits the 2 MB
    // partial array; else 8 slices (1 MB, known-good footprint).
    const size_t need16 = (size_t)16 * N_TOK * 8 + (size_t)NE * 8 + 64;
    const int nslice = (ws_size >= need16) ? 16 : 8;
    const int csl = NE / nslice;

    char* ws = (char*)d_ws;
    u64*   part    = (u64*)ws;                                    // nslice*16384*8
    float* ne      = (float*)(ws + (size_t)nslice * N_TOK * 8);   // 16 KB
    int*   hist    = (int*)(ne + NE);                             // 16 KB
    float* lossAcc = (float*)(hist + NE);                         // 4 B

    hipLaunchKernelGGL(prep_kernel, dim3(16), dim3(256), 0, stream,
                       cb, ne, hist, lossAcc);
    hipLaunchKernelGGL(dist_argmin_kernel,
                       dim3(N_TOK / (TPB * TOKPT), nslice), dim3(TPB), 0, stream,
                       z, cb, ne, part, csl);
    hipLaunchKernelGGL(reduce_gather_kernel, dim3(256), dim3(256), 0, stream,
                       z, cb, part, hist, lossAcc, out, nslice);
    hipLaunchKernelGGL(finalize_kernel, dim3(1), dim3(256), 0, stream,
                       hist, lossAcc, out);
}